// Round 12
// baseline (228.446 us; speedup 1.0000x reference)
//
#include <hip/hip_runtime.h>

#define FD 128  // feature dim (H = O = 128)
#define NB 256  // sort buckets / hist blocks

typedef __attribute__((ext_vector_type(8))) short bf16x8;
typedef __attribute__((ext_vector_type(8))) unsigned short u16x8;
typedef __attribute__((ext_vector_type(4))) float f32x4;

__device__ __forceinline__ float lrelu(float x) { return x > 0.f ? x : 0.2f * x; }

__device__ __forceinline__ unsigned short f2bf(float f) {
    unsigned int u = __float_as_uint(f);
    u = (u + 0x7FFFu + ((u >> 16) & 1u)) >> 16;
    return (unsigned short)u;
}
__device__ __forceinline__ float bf2f(unsigned short h) {
    return __uint_as_float((unsigned int)h << 16);
}

// ---------- MFMA GEMM body (shared): C[n,128] = act(A @ W (+ b)), bf16 out ----------
template <bool BIAS_RELU, bool AV, bool AFP32, bool WF32>
__device__ __forceinline__ void gemm_body(const void* __restrict__ Av,
                                          const void* __restrict__ Wsrc,
                                          const float* __restrict__ b,
                                          unsigned short* __restrict__ C,
                                          const float* __restrict__ av_s,
                                          const float* __restrict__ av_d,
                                          float* asrc, float* adst, int n, int bid) {
    __shared__ unsigned short Wt[FD][136];
    if (WF32) {
        const float* W = (const float*)Wsrc;
        for (int idx = threadIdx.x; idx < FD * FD; idx += 512) {
            int k = idx >> 7, j = idx & 127;
            Wt[j][k] = f2bf(W[idx]);
        }
    } else {
        const unsigned short* Wtg = (const unsigned short*)Wsrc;
        #pragma unroll
        for (int it = 0; it < 4; ++it) {
            int idx = (it * 512 + threadIdx.x) * 8;
            int j = idx >> 7, k = idx & 127;
            *(u16x8*)&Wt[j][k] = *(const u16x8*)&Wtg[idx];
        }
    }
    __syncthreads();

    const int wid = threadIdx.x >> 6;
    const int lane = threadIdx.x & 63;
    const int lm = lane & 15;
    const int lh = lane >> 4;
    const int row0 = bid * 128 + wid * 16;

    const int arow = min(row0 + lm, n - 1);
    bf16x8 a0, a1, a2, a3;
    if (AFP32) {
        const float* Ar = (const float*)Av + (size_t)arow * FD + lh * 8;
        #pragma unroll
        for (int kk = 0; kk < 4; ++kk) {
            float4 lo = *(const float4*)(Ar + kk * 32);
            float4 hi = *(const float4*)(Ar + kk * 32 + 4);
            bf16x8 a;
            a[0] = (short)f2bf(lo.x); a[1] = (short)f2bf(lo.y);
            a[2] = (short)f2bf(lo.z); a[3] = (short)f2bf(lo.w);
            a[4] = (short)f2bf(hi.x); a[5] = (short)f2bf(hi.y);
            a[6] = (short)f2bf(hi.z); a[7] = (short)f2bf(hi.w);
            if (kk == 0) a0 = a; else if (kk == 1) a1 = a; else if (kk == 2) a2 = a; else a3 = a;
        }
    } else {
        const unsigned short* Ar = (const unsigned short*)Av + (size_t)arow * FD + lh * 8;
        a0 = *(const bf16x8*)(Ar);
        a1 = *(const bf16x8*)(Ar + 32);
        a2 = *(const bf16x8*)(Ar + 64);
        a3 = *(const bf16x8*)(Ar + 96);
    }

    f32x4 acc[8];
    #pragma unroll
    for (int nt = 0; nt < 8; ++nt) acc[nt] = (f32x4){0.f, 0.f, 0.f, 0.f};

    #pragma unroll
    for (int nt = 0; nt < 8; ++nt) {
        const unsigned short* wp = &Wt[nt * 16 + lm][lh * 8];
        bf16x8 b0 = *(const bf16x8*)(wp);
        bf16x8 b1 = *(const bf16x8*)(wp + 32);
        bf16x8 b2 = *(const bf16x8*)(wp + 64);
        bf16x8 b3 = *(const bf16x8*)(wp + 96);
        acc[nt] = __builtin_amdgcn_mfma_f32_16x16x32_bf16(a0, b0, acc[nt], 0, 0, 0);
        acc[nt] = __builtin_amdgcn_mfma_f32_16x16x32_bf16(a1, b1, acc[nt], 0, 0, 0);
        acc[nt] = __builtin_amdgcn_mfma_f32_16x16x32_bf16(a2, b2, acc[nt], 0, 0, 0);
        acc[nt] = __builtin_amdgcn_mfma_f32_16x16x32_bf16(a3, b3, acc[nt], 0, 0, 0);
    }

    #pragma unroll
    for (int nt = 0; nt < 8; ++nt) {
        const int c = nt * 16 + lm;
        float bv = 0.f;
        if (BIAS_RELU) bv = b[c];
        #pragma unroll
        for (int r = 0; r < 4; ++r) {
            const int row = row0 + 4 * lh + r;
            float v = acc[nt][r];
            if (BIAS_RELU) v = fmaxf(v + bv, 0.f);
            if (row < n) C[(size_t)row * FD + c] = f2bf(v);
        }
    }

    if (AV) {
        float asv[8], adv[8];
        #pragma unroll
        for (int nt = 0; nt < 8; ++nt) {
            asv[nt] = av_s[nt * 16 + lm];
            adv[nt] = av_d[nt * 16 + lm];
        }
        #pragma unroll
        for (int r = 0; r < 4; ++r) {
            float ps = 0.f, pd = 0.f;
            #pragma unroll
            for (int nt = 0; nt < 8; ++nt) {
                ps = fmaf(acc[nt][r], asv[nt], ps);
                pd = fmaf(acc[nt][r], adv[nt], pd);
            }
            #pragma unroll
            for (int m = 1; m < 16; m <<= 1) {
                ps += __shfl_xor(ps, m);
                pd += __shfl_xor(pd, m);
            }
            const int row = row0 + 4 * lh + r;
            if (lm == 0 && row < n) { asrc[row] = ps; adst[row] = pd; }
        }
    }
}

// ---------- mega kernel 0: emb-GEMM | bucket-hist | W cvt | zero ----------
__global__ __launch_bounds__(512) void k_mega0(const float* __restrict__ x,
                                               const float* __restrict__ W_emb,
                                               const float* __restrict__ b_emb,
                                               unsigned short* __restrict__ h0,
                                               const int* __restrict__ dst, int* ghist,
                                               int e, int chunk,
                                               const float* __restrict__ W1,
                                               const float* __restrict__ W2,
                                               const float* __restrict__ Wg,
                                               unsigned short* __restrict__ Wt4,
                                               float* out, int* counters, int n, int gb) {
    const int bx = blockIdx.x;
    if (bx < gb) {
        gemm_body<true, false, true, true>(x, W_emb, b_emb, h0,
                                           nullptr, nullptr, nullptr, nullptr, n, bx);
        return;
    }
    if (bx < gb + 256) {
        __shared__ int h[256];
        if (threadIdx.x < 256) h[threadIdx.x] = 0;
        __syncthreads();
        const int blk = bx - gb;
        const int i0 = blk * chunk;
        const int i1 = min(i0 + chunk, e);
        for (int i = i0 + threadIdx.x; i < i1; i += 512)
            atomicAdd(&h[dst[i] >> 8], 1);
        __syncthreads();
        if (threadIdx.x < 256) ghist[threadIdx.x * NB + blk] = h[threadIdx.x];
        return;
    }
    if (bx < gb + 256 + 96) {
        const int elem = (bx - gb - 256) * 512 + threadIdx.x;   // [0, 49152)
        const int sel = elem >> 14;
        const int within = elem & 16383;
        const int k = within >> 7, j = within & 127;
        const float* Ws = (sel == 0) ? W1 : (sel == 1) ? W2 : Wg;
        Wt4[sel * FD * FD + j * FD + k] = f2bf(Ws[within]);
        return;
    }
    // zero block
    if (threadIdx.x < 128) out[threadIdx.x] = 0.f;
    if (threadIdx.x == 128) counters[0] = 0;   // reduce counter
    if (threadIdx.x == 129) counters[1] = 0;   // scan counter
}

// ---------- standalone GEMM ----------
template <bool AV>
__global__ __launch_bounds__(512) void k_gemm(const unsigned short* __restrict__ A,
                                              const unsigned short* __restrict__ Wtg,
                                              unsigned short* __restrict__ C,
                                              const float* __restrict__ av_s,
                                              const float* __restrict__ av_d,
                                              float* asrc, float* adst, int n) {
    gemm_body<false, AV, false, false>(A, Wtg, nullptr, C, av_s, av_d, asrc, adst, n, blockIdx.x);
}

// ---------- scan (scan2 folded in via last-block) ----------
// S = per-block inclusive scan of v; bsum = inclusive scan of block totals
__global__ __launch_bounds__(256) void k_scan1(const int* __restrict__ v, int* S,
                                               int* bsum, int* counters, int n) {
    __shared__ int lds[256];
    int i = blockIdx.x * 256 + threadIdx.x;
    int x = (i < n) ? v[i] : 0;
    lds[threadIdx.x] = x;
    __syncthreads();
    for (int off = 1; off < 256; off <<= 1) {
        int t = (threadIdx.x >= off) ? lds[threadIdx.x - off] : 0;
        __syncthreads();
        lds[threadIdx.x] += t;
        __syncthreads();
    }
    if (i < n) S[i] = lds[threadIdx.x];
    if (threadIdx.x == 255) bsum[blockIdx.x] = lds[255];
    // last block scans bsum (device-coherent via atomics)
    __threadfence();
    __shared__ int lastflag;
    if (threadIdx.x == 0) {
        int old = atomicAdd(&counters[1], 1);
        lastflag = (old == (int)gridDim.x - 1);
    }
    __syncthreads();
    if (!lastflag) return;
    int bv = atomicAdd(&bsum[threadIdx.x], 0);   // coherent read
    lds[threadIdx.x] = bv;
    __syncthreads();
    for (int off = 1; off < 256; off <<= 1) {
        int t = (threadIdx.x >= off) ? lds[threadIdx.x - off] : 0;
        __syncthreads();
        lds[threadIdx.x] += t;
        __syncthreads();
    }
    bsum[threadIdx.x] = lds[threadIdx.x];
}

// exclusive offset on the fly: idx = bin*NB + blk
// S_excl[idx] = S_incl[idx] - v[idx] + (bin>0 ? bsum[bin-1] : 0)

// ---------- bucket scatter: (d<<16)|s into bucket-contiguous pk ----------
__global__ __launch_bounds__(256) void k_bscatter(const int* __restrict__ dst,
                                                  const int* __restrict__ src,
                                                  const int* __restrict__ S,
                                                  const int* __restrict__ gh,
                                                  const int* __restrict__ bsum,
                                                  int* pk, int e, int chunk) {
    __shared__ int cur[256];
    const int t = threadIdx.x;
    const int idx = t * NB + blockIdx.x;
    cur[t] = S[idx] - gh[idx] + ((t > 0) ? bsum[t - 1] : 0);
    __syncthreads();
    const int i0 = blockIdx.x * chunk;
    const int i1 = min(i0 + chunk, e);
    for (int i = i0 + t; i < i1; i += 256) {
        int d = dst[i];
        int s = src[i];
        int pos = atomicAdd(&cur[d >> 8], 1);
        pk[pos] = (d << 16) | s;
    }
}

// ---------- per-bucket finalize: cnt, rp (segment END), dinv, col ----------
__global__ __launch_bounds__(256) void k_bfinal(const int* __restrict__ pk,
                                                const int* __restrict__ S,
                                                const int* __restrict__ gh,
                                                const int* __restrict__ bsum,
                                                int* cnt, int* rp, float* dinv,
                                                int* col, int e, int n) {
    __shared__ int cl[256];
    __shared__ int sc[256];
    const int b = blockIdx.x;
    const int i0 = b * NB;
    const int base = S[i0] - gh[i0] + ((b > 0) ? bsum[b - 1] : 0);
    int end;
    if (b < 255) {
        const int i1 = (b + 1) * NB;
        end = S[i1] - gh[i1] + bsum[b];
    } else {
        end = e;
    }
    cl[threadIdx.x] = 0;
    __syncthreads();
    for (int j = base + threadIdx.x; j < end; j += 256)
        atomicAdd(&cl[(pk[j] >> 16) & 255], 1);
    __syncthreads();
    sc[threadIdx.x] = cl[threadIdx.x];
    __syncthreads();
    for (int off = 1; off < 256; off <<= 1) {
        int t = (threadIdx.x >= off) ? sc[threadIdx.x - off] : 0;
        __syncthreads();
        sc[threadIdx.x] += t;
        __syncthreads();
    }
    const int c = cl[threadIdx.x];
    const int incl = sc[threadIdx.x];
    const int d = b * 256 + threadIdx.x;
    if (d < n) {
        cnt[d] = c;
        rp[d] = base + incl;
        dinv[d] = rsqrtf((float)c + 1.0f);
    }
    __syncthreads();
    sc[threadIdx.x] = base + incl - c;
    __syncthreads();
    for (int j = base + threadIdx.x; j < end; j += 256) {
        int p = pk[j];
        int pos = atomicAdd(&sc[(p >> 16) & 255], 1);
        col[pos] = p & 0xFFFF;
    }
}

// ---------- fused gather over bf16 rows, bf16 out ----------
template <int MODE>
__global__ __launch_bounds__(256) void k_gather(const unsigned short* __restrict__ m,
                                                const int* __restrict__ col,
                                                const int* __restrict__ rp,
                                                const int* __restrict__ cnt,
                                                const float* __restrict__ dinv,
                                                const float* __restrict__ bias,
                                                const float* __restrict__ asrc,
                                                const float* __restrict__ adst,
                                                unsigned short* __restrict__ out, int n) {
    const int wave = threadIdx.x >> 6;
    const int lane = threadIdx.x & 63;
    const int q = lane >> 4;
    const int l16 = lane & 15;
    const int d = blockIdx.x * 4 + wave;
    if (d >= n) return;
    const int c0 = l16 * 8;

    const float sd = (MODE == 0) ? dinv[d] : adst[d];

    float acc[8];
    #pragma unroll
    for (int i = 0; i < 8; ++i) acc[i] = 0.f;
    float denom = 0.f;

    if (q == 0) {  // self term
        float w = (MODE == 0) ? sd * sd : expf(lrelu(asrc[d] + sd));
        u16x8 u = *(const u16x8*)(m + (size_t)d * FD + c0);
        #pragma unroll
        for (int i = 0; i < 8; ++i) acc[i] = w * bf2f(u[i]);
        denom = w;
    }

    const int deg = cnt[d];
    const int beg = rp[d] - deg;
    int j = q;

    for (; j + 12 < deg; j += 16) {
        const int s0 = col[beg + j];
        const int s1 = col[beg + j + 4];
        const int s2 = col[beg + j + 8];
        const int s3 = col[beg + j + 12];
        const u16x8 u0 = *(const u16x8*)(m + (size_t)s0 * FD + c0);
        const u16x8 u1 = *(const u16x8*)(m + (size_t)s1 * FD + c0);
        const u16x8 u2 = *(const u16x8*)(m + (size_t)s2 * FD + c0);
        const u16x8 u3 = *(const u16x8*)(m + (size_t)s3 * FD + c0);
        float w0, w1, w2, w3;
        if (MODE == 0) {
            w0 = sd * dinv[s0]; w1 = sd * dinv[s1];
            w2 = sd * dinv[s2]; w3 = sd * dinv[s3];
        } else {
            w0 = expf(lrelu(asrc[s0] + sd)); w1 = expf(lrelu(asrc[s1] + sd));
            w2 = expf(lrelu(asrc[s2] + sd)); w3 = expf(lrelu(asrc[s3] + sd));
        }
        #pragma unroll
        for (int i = 0; i < 8; ++i) {
            acc[i] = fmaf(w0, bf2f(u0[i]), acc[i]);
            acc[i] = fmaf(w1, bf2f(u1[i]), acc[i]);
            acc[i] = fmaf(w2, bf2f(u2[i]), acc[i]);
            acc[i] = fmaf(w3, bf2f(u3[i]), acc[i]);
        }
        if (MODE == 1) denom += w0 + w1 + w2 + w3;
    }
    for (; j < deg; j += 4) {
        const int s = col[beg + j];
        const u16x8 u = *(const u16x8*)(m + (size_t)s * FD + c0);
        float w;
        if (MODE == 0) w = sd * dinv[s];
        else           w = expf(lrelu(asrc[s] + sd));
        #pragma unroll
        for (int i = 0; i < 8; ++i) acc[i] = fmaf(w, bf2f(u[i]), acc[i]);
        if (MODE == 1) denom += w;
    }

    #pragma unroll
    for (int i = 0; i < 8; ++i) {
        acc[i] += __shfl_xor(acc[i], 16);
        acc[i] += __shfl_xor(acc[i], 32);
    }
    if (MODE == 1) {
        denom += __shfl_xor(denom, 16);
        denom += __shfl_xor(denom, 32);
    }

    if (q == 0) {
        float o[8];
        if (MODE == 0) {
            #pragma unroll
            for (int i = 0; i < 8; ++i) o[i] = fmaxf(acc[i] + bias[c0 + i], 0.f);
        } else {
            float inv = 1.0f / denom;
            #pragma unroll
            for (int i = 0; i < 8; ++i) o[i] = acc[i] * inv;
        }
        u16x8 ou;
        #pragma unroll
        for (int i = 0; i < 8; ++i) ou[i] = f2bf(o[i]);
        *(u16x8*)(out + (size_t)d * FD + c0) = ou;
    }
}

// ---------- mean over nodes + final scale/bias (coalesced, last-block) ----------
// block reads 16 contiguous rows/iter; thread (rg,cg) loads u16x8 -> fully
// coalesced 4KB per block-iter, 7+ independent loads in flight per thread.
__global__ __launch_bounds__(256) void k_reduce(const unsigned short* __restrict__ val,
                                                float* out, const float* __restrict__ bg,
                                                int* counters, int n, float invn) {
    const int rg = threadIdx.x >> 4;   // 0..15 row-in-group
    const int cg = threadIdx.x & 15;   // col group (8 cols)
    const int c0 = cg * 8;
    float acc[8];
    #pragma unroll
    for (int i = 0; i < 8; ++i) acc[i] = 0.f;

    for (int i = blockIdx.x * 16 + rg; i < n; i += gridDim.x * 16) {
        u16x8 u = *(const u16x8*)(val + (size_t)i * FD + c0);
        #pragma unroll
        for (int k = 0; k < 8; ++k) acc[k] += bf2f(u[k]);
    }

    __shared__ float lds[16][129];
    #pragma unroll
    for (int k = 0; k < 8; ++k) lds[rg][c0 + k] = acc[k];
    __syncthreads();
    if (threadIdx.x < 128) {
        float s = 0.f;
        #pragma unroll
        for (int k = 0; k < 16; ++k) s += lds[k][threadIdx.x];
        atomicAdd(&out[threadIdx.x], s);
    }
    __syncthreads();
    __threadfence();
    __shared__ int lastflag;
    if (threadIdx.x == 0) {
        int old = atomicAdd(&counters[0], 1);
        lastflag = (old == (int)gridDim.x - 1);
    }
    __syncthreads();
    if (lastflag) {
        __threadfence();
        if (threadIdx.x < 128) {
            float v = atomicAdd(&out[threadIdx.x], 0.0f);  // coherent read
            out[threadIdx.x] = v * invn + bg[threadIdx.x];
        }
    }
}

// ---------- launch ----------
extern "C" void kernel_launch(void* const* d_in, const int* in_sizes, int n_in,
                              void* d_out, int out_size, void* d_ws, size_t ws_size,
                              hipStream_t stream) {
    const float* x      = (const float*)d_in[0];
    const int*   ei     = (const int*)d_in[1];
    const float* W_emb  = (const float*)d_in[2];
    const float* b_emb  = (const float*)d_in[3];
    const float* W1     = (const float*)d_in[4];
    const float* b1     = (const float*)d_in[5];
    const float* W2     = (const float*)d_in[6];
    const float* b2     = (const float*)d_in[7];
    const float* Wg     = (const float*)d_in[8];
    const float* a_src  = (const float*)d_in[9];
    const float* a_dst  = (const float*)d_in[10];
    const float* bg     = (const float*)d_in[11];

    const int n = in_sizes[0] / FD;   // 50000
    const int e = in_sizes[1] / 2;    // 800000
    const int* src = ei;
    const int* dst = ei + e;

    unsigned short* bufA = (unsigned short*)d_ws;           // n*128 bf16
    unsigned short* bufB = bufA + (size_t)n * FD;           // n*128 bf16
    unsigned short* Wt4  = bufB + (size_t)n * FD;           // 3 * 128*128 bf16
    float* dinv  = (float*)(Wt4 + 3 * FD * FD);
    float* asrc  = dinv + n;
    float* adst  = asrc + n;
    int*   cnt   = (int*)(adst + n);
    int*   rp    = cnt + n;
    int*   col   = rp + n;
    int*   pk    = col + e;
    int*   ghist = pk + e;            // 65536
    int*   Sg    = ghist + NB * 256;  // 65536
    int*   bsum  = Sg + NB * 256;     // 256
    int*   counters = bsum + 256;     // 2

    const dim3 B(256);
    const int chunk  = (e + NB - 1) / NB;
    const int gnode4 = (n + 3) / 4;
    const int gb128  = (n + 127) / 128;   // 391

    // 1) mega0: emb-GEMM | bhist | wcvt | zero   (all independent)
    k_mega0<<<gb128 + 256 + 96 + 1, 512, 0, stream>>>(x, W_emb, b_emb, bufB,
                                                      dst, ghist, e, chunk,
                                                      W1, W2, Wg, Wt4,
                                                      (float*)d_out, counters, n, gb128);
    // 2-4) sort
    k_scan1<<<256, B, 0, stream>>>(ghist, Sg, bsum, counters, NB * 256);
    k_bscatter<<<NB, B, 0, stream>>>(dst, src, Sg, ghist, bsum, pk, e, chunk);
    k_bfinal<<<256, B, 0, stream>>>(pk, Sg, ghist, bsum, cnt, rp, dinv, col, e, n);

    // 5-6) GCN layer 1
    k_gemm<false><<<gb128, 512, 0, stream>>>(bufB, Wt4 + 0 * FD * FD, bufA,
                                             nullptr, nullptr, nullptr, nullptr, n);
    k_gather<0><<<gnode4, B, 0, stream>>>(bufA, col, rp, cnt, dinv, b1,
                                          nullptr, nullptr, bufB, n);
    // 7-8) GCN layer 2
    k_gemm<false><<<gb128, 512, 0, stream>>>(bufB, Wt4 + 1 * FD * FD, bufA,
                                             nullptr, nullptr, nullptr, nullptr, n);
    k_gather<0><<<gnode4, B, 0, stream>>>(bufA, col, rp, cnt, dinv, b2,
                                          nullptr, nullptr, bufB, n);
    // 9-10) GAT
    k_gemm<true><<<gb128, 512, 0, stream>>>(bufB, Wt4 + 2 * FD * FD, bufA,
                                            a_src, a_dst, asrc, adst, n);
    k_gather<1><<<gnode4, B, 0, stream>>>(bufA, col, rp, cnt, nullptr, nullptr,
                                          asrc, adst, bufB, n);
    // 11) mean + final
    k_reduce<<<384, B, 0, stream>>>(bufB, (float*)d_out, bg, counters, n, 1.0f / n);
}